// Round 11
// baseline (62.351 us; speedup 1.0000x reference)
//
#include <hip/hip_runtime.h>

#define NPTS 16384
#define NBATCH 256
constexpr int THREADS = 1024;          // 16 waves
constexpr int NW      = THREADS / 64;
constexpr int HALFPTS = NPTS / 2;      // 8192 points per block
constexpr int NBLK    = NBATCH * 2;    // 512 blocks -> 2/CU -> 32 waves/CU
// wave w owns [w*512, (w+1)*512) of its half; lane i owns 4-pt mini-segments
// at w*512 + g*256 + i*4 (g=0,1) -> every global load is 64x16B contiguous.

struct Ws {
  unsigned int counter;     // ticket
  unsigned int pad[3];
  unsigned int flags[NBATCH];
  float vx[NBATCH], vy[NBATCH], vz[NBATCH];
};
constexpr size_t WS_ZERO_BYTES = sizeof(unsigned int) * (4 + NBATCH);

__device__ __forceinline__ float4 ld4(const float* p) {
  return *reinterpret_cast<const float4*>(p);
}

__global__ __launch_bounds__(THREADS, 8) void half_row_kernel(
    const float* __restrict__ o3, const float* __restrict__ s3,
    const float* __restrict__ o2, const float* __restrict__ s2,
    const float* __restrict__ df, Ws* __restrict__ ws,
    float* __restrict__ out) {
  const int t = threadIdx.x;
  const int lane = t & 63;
  const int wave = t >> 6;

  __shared__ unsigned int ticket_s;
  __shared__ float wtot[3][NW];
  __shared__ float carry_s[3];
  __shared__ float redbuf[NW];

  // ticket: first NBATCH tickets are producers (lower halves) -> never starve
  if (t == 0) ticket_s = atomicAdd(&ws->counter, 1u);
  __syncthreads();
  const int vb = (int)ticket_s;
  const bool prod = vb < NBATCH;
  const int b = prod ? vb : vb - NBATCH;
  const int hoff = prod ? 0 : HALFPTS;

  const float* r3p = s3 + (size_t)b * 3 * NPTS + hoff;
  const float* t3p = r3p + NPTS;
  const float* p3p = r3p + 2 * NPTS;
  const float* r2p = s2 + (size_t)b * 3 * NPTS + hoff;
  const float* t2p = r2p + NPTS;
  const float* p2p = r2p + 2 * NPTS;
  const float* dtp = df + (size_t)b * 2 * NPTS + hoff;
  const float* dpp = dtp + NPTS;

  const int wbase = wave * 512;

  // ---- Phase 1: coalesced stream, trig, wave-local prefix (registers) ----
  float px[2][4], py[2][4], pz[2][4];   // inclusive prefix within mini-seg
  float segx[2], segy[2], segz[2];      // exclusive mini-seg offset in wave
  float runx = 0.f, runy = 0.f, runz = 0.f;
  #pragma unroll
  for (int g = 0; g < 2; ++g) {
    const int idx = wbase + g * 256 + lane * 4;
    float4 R3 = ld4(r3p + idx), T3 = ld4(t3p + idx);
    float4 P3 = ld4(p3p + idx), R2 = ld4(r2p + idx);
    float4 T2 = ld4(t2p + idx), P2 = ld4(p2p + idx);
    float4 DT = ld4(dtp + idx), DP = ld4(dpp + idx);
    float sx = 0.f, sy = 0.f, sz = 0.f;
    #pragma unroll
    for (int k = 0; k < 4; ++k) {
      float r3v = ((const float*)&R3)[k];
      float th3 = ((const float*)&T3)[k] + ((const float*)&DT)[k];
      float ph3 = ((const float*)&P3)[k] + ((const float*)&DP)[k];
      float r2v = ((const float*)&R2)[k];
      float th2 = ((const float*)&T2)[k];
      float ph2 = ((const float*)&P2)[k];
      float st3 = __sinf(th3), ct3 = __cosf(th3);
      float sp3 = __sinf(ph3), cp3 = __cosf(ph3);
      float st2 = __sinf(th2), ct2 = __cosf(th2);
      float sp2 = __sinf(ph2), cp2 = __cosf(ph2);
      sx += r3v * st3 * cp3 - r2v * st2 * cp2; px[g][k] = sx;
      sy += r3v * st3 * sp3 - r2v * st2 * sp2; py[g][k] = sy;
      sz += r3v * ct3 - r2v * ct2;             pz[g][k] = sz;
    }
    // wave scan of mini-segment totals (j-order: g-major, then lane)
    float ix = sx, iy = sy, iz = sz;
    #pragma unroll
    for (int off = 1; off < 64; off <<= 1) {
      float ax = __shfl_up(ix, off, 64);
      float ay = __shfl_up(iy, off, 64);
      float az = __shfl_up(iz, off, 64);
      if (lane >= off) { ix += ax; iy += ay; iz += az; }
    }
    segx[g] = runx + ix - sx;
    segy[g] = runy + iy - sy;
    segz[g] = runz + iz - sz;
    runx += __shfl(ix, 63, 64);
    runy += __shfl(iy, 63, 64);
    runz += __shfl(iz, 63, 64);
  }

  if (lane == 0) { wtot[0][wave] = runx; wtot[1][wave] = runy; wtot[2][wave] = runz; }
  __syncthreads();

  // wave offset within block + block total
  float wx = 0.f, wy = 0.f, wz = 0.f;
  float btx = 0.f, bty = 0.f, btz = 0.f;
  #pragma unroll
  for (int w = 0; w < NW; ++w) {
    float vx = wtot[0][w], vy = wtot[1][w], vz = wtot[2][w];
    if (w < wave) { wx += vx; wy += vy; wz += vz; }
    btx += vx; bty += vy; btz += vz;
  }

  // ---- depth-1 handoff: producer publishes, consumer polls (overlapped) ----
  if (t == 0) {
    if (prod) {
      __hip_atomic_store(&ws->vx[b], btx, __ATOMIC_RELAXED, __HIP_MEMORY_SCOPE_AGENT);
      __hip_atomic_store(&ws->vy[b], bty, __ATOMIC_RELAXED, __HIP_MEMORY_SCOPE_AGENT);
      __hip_atomic_store(&ws->vz[b], btz, __ATOMIC_RELAXED, __HIP_MEMORY_SCOPE_AGENT);
      __hip_atomic_store(&ws->flags[b], 1u, __ATOMIC_RELEASE, __HIP_MEMORY_SCOPE_AGENT);
      carry_s[0] = 0.f; carry_s[1] = 0.f; carry_s[2] = 0.f;
    } else {
      while (__hip_atomic_load(&ws->flags[b], __ATOMIC_ACQUIRE,
                               __HIP_MEMORY_SCOPE_AGENT) == 0u) {
        __builtin_amdgcn_s_sleep(4);
      }
      carry_s[0] = __hip_atomic_load(&ws->vx[b], __ATOMIC_RELAXED, __HIP_MEMORY_SCOPE_AGENT);
      carry_s[1] = __hip_atomic_load(&ws->vy[b], __ATOMIC_RELAXED, __HIP_MEMORY_SCOPE_AGENT);
      carry_s[2] = __hip_atomic_load(&ws->vz[b], __ATOMIC_RELAXED, __HIP_MEMORY_SCOPE_AGENT);
    }
  }
  __syncthreads();

  // row carry = origin diff (+ lower-half total for the upper half)
  const float ox = o3[b * 3 + 0] - o2[b * 3 + 0];
  const float oy = o3[b * 3 + 1] - o2[b * 3 + 1];
  const float oz = o3[b * 3 + 2] - o2[b * 3 + 2];
  const float Cx = ox + carry_s[0] + wx;
  const float Cy = oy + carry_s[1] + wy;
  const float Cz = oz + carry_s[2] + wz;

  // ---- Phase 2: abs over in-register prefixes ----
  float acc = 0.f;
  #pragma unroll
  for (int g = 0; g < 2; ++g) {
    const float gx = Cx + segx[g], gy = Cy + segy[g], gz = Cz + segz[g];
    #pragma unroll
    for (int k = 0; k < 4; ++k) {
      acc += fabsf(gx + px[g][k]) + fabsf(gy + py[g][k]) + fabsf(gz + pz[g][k]);
    }
  }
  if (prod && t == 0) acc += fabsf(ox) + fabsf(oy) + fabsf(oz);  // j=0 term

  // ---- block reduction + one atomic per block ----
  #pragma unroll
  for (int off = 32; off > 0; off >>= 1) acc += __shfl_down(acc, off, 64);
  if (lane == 0) redbuf[wave] = acc;
  __syncthreads();
  if (t == 0) {
    float s = 0.f;
    #pragma unroll
    for (int w = 0; w < NW; ++w) s += redbuf[w];
    atomicAdd(out, s * (1.0f / (float)(NPTS + 1)));
  }
}

extern "C" void kernel_launch(void* const* d_in, const int* in_sizes, int n_in,
                              void* d_out, int out_size, void* d_ws, size_t ws_size,
                              hipStream_t stream) {
  const float* o3 = (const float*)d_in[0];  // origin_3D      (B,3,1)
  const float* s3 = (const float*)d_in[1];  // spherical_3D   (B,3,N)
  const float* o2 = (const float*)d_in[2];  // origin_2D      (B,3,1)
  const float* s2 = (const float*)d_in[3];  // spherical_2D   (B,3,N)
  const float* df = (const float*)d_in[4];  // deformation    (B,2,N)
  float* out = (float*)d_out;
  Ws* ws = (Ws*)d_ws;

  // ticket + flags must be zero each (replayed) launch; out accumulates.
  hipMemsetAsync(ws, 0, WS_ZERO_BYTES, stream);
  hipMemsetAsync(out, 0, sizeof(float) * out_size, stream);
  half_row_kernel<<<NBLK, THREADS, 0, stream>>>(o3, s3, o2, s2, df, ws, out);
}

// Round 12
// 34.113 us; speedup vs baseline: 1.8278x; 1.8278x over previous
//
#include <hip/hip_runtime.h>

#define NPTS 16384
#define NBATCH 256
constexpr int THREADS = 1024;            // 16 waves; one block per row/CU
constexpr int NW      = THREADS / 64;    // 16 waves
// wave w owns points [w*1024,(w+1)*1024); lane i owns 4-pt mini-segments at
// w*1024 + g*256 + i*4 (g=0..3) -> every global load is 64x16B contiguous.
// Depth-1 software pipeline: chunk g+1's 8 float4 loads are issued before
// chunk g's trig, so ~16KB/wave stays in flight.

__device__ __forceinline__ float4 ld4(const float* p) {
  return *reinterpret_cast<const float4*>(p);
}

struct Pack8 { float4 R3, T3, P3, R2, T2, P2, DT, DP; };

__device__ __forceinline__ Pack8 load_pack(
    const float* r3p, const float* t3p, const float* p3p,
    const float* r2p, const float* t2p, const float* p2p,
    const float* dtp, const float* dpp, int idx) {
  Pack8 p;
  p.R3 = ld4(r3p + idx); p.T3 = ld4(t3p + idx);
  p.P3 = ld4(p3p + idx); p.R2 = ld4(r2p + idx);
  p.T2 = ld4(t2p + idx); p.P2 = ld4(p2p + idx);
  p.DT = ld4(dtp + idx); p.DP = ld4(dpp + idx);
  return p;
}

__global__ __launch_bounds__(THREADS, 4) void row_loss_kernel(
    const float* __restrict__ o3, const float* __restrict__ s3,
    const float* __restrict__ o2, const float* __restrict__ s2,
    const float* __restrict__ df, float* __restrict__ out) {
  const int b = blockIdx.x;
  const int t = threadIdx.x;
  const int lane = t & 63;
  const int wave = t >> 6;

  const float* r3p = s3 + (size_t)b * 3 * NPTS;
  const float* t3p = r3p + NPTS;
  const float* p3p = r3p + 2 * NPTS;
  const float* r2p = s2 + (size_t)b * 3 * NPTS;
  const float* t2p = r2p + NPTS;
  const float* p2p = r2p + 2 * NPTS;
  const float* dtp = df + (size_t)b * 2 * NPTS;
  const float* dpp = dtp + NPTS;

  const int wbase = wave * 1024;

  // ---- Phase 1: pipelined stream + trig + per-mini-segment prefix ----
  float px[4][4], py[4][4], pz[4][4];   // inclusive prefix within mini-seg
  float mx[4], my[4], mz[4];            // mini-segment totals

  Pack8 cur = load_pack(r3p, t3p, p3p, r2p, t2p, p2p, dtp, dpp,
                        wbase + 0 * 256 + lane * 4);
  #pragma unroll
  for (int g = 0; g < 4; ++g) {
    Pack8 nxt;
    if (g < 3) {
      nxt = load_pack(r3p, t3p, p3p, r2p, t2p, p2p, dtp, dpp,
                      wbase + (g + 1) * 256 + lane * 4);
    }
    float sx = 0.f, sy = 0.f, sz = 0.f;
    #pragma unroll
    for (int k = 0; k < 4; ++k) {
      float r3v = ((const float*)&cur.R3)[k];
      float th3 = ((const float*)&cur.T3)[k] + ((const float*)&cur.DT)[k];
      float ph3 = ((const float*)&cur.P3)[k] + ((const float*)&cur.DP)[k];
      float r2v = ((const float*)&cur.R2)[k];
      float th2 = ((const float*)&cur.T2)[k];
      float ph2 = ((const float*)&cur.P2)[k];
      float st3 = __sinf(th3), ct3 = __cosf(th3);
      float sp3 = __sinf(ph3), cp3 = __cosf(ph3);
      float st2 = __sinf(th2), ct2 = __cosf(th2);
      float sp2 = __sinf(ph2), cp2 = __cosf(ph2);
      sx += r3v * st3 * cp3 - r2v * st2 * cp2; px[g][k] = sx;
      sy += r3v * st3 * sp3 - r2v * st2 * sp2; py[g][k] = sy;
      sz += r3v * ct3 - r2v * ct2;             pz[g][k] = sz;
    }
    mx[g] = sx; my[g] = sy; mz[g] = sz;
    cur = nxt;
  }

  // ---- Phase 2: wave scan in j-order (g-major, then lane) ----
  float runx = 0.f, runy = 0.f, runz = 0.f;
  float segx[4], segy[4], segz[4];
  #pragma unroll
  for (int g = 0; g < 4; ++g) {
    float ix = mx[g], iy = my[g], iz = mz[g];
    #pragma unroll
    for (int off = 1; off < 64; off <<= 1) {
      float ax = __shfl_up(ix, off, 64);
      float ay = __shfl_up(iy, off, 64);
      float az = __shfl_up(iz, off, 64);
      if (lane >= off) { ix += ax; iy += ay; iz += az; }
    }
    segx[g] = runx + ix - mx[g];
    segy[g] = runy + iy - my[g];
    segz[g] = runz + iz - mz[g];
    runx += __shfl(ix, 63, 64);
    runy += __shfl(iy, 63, 64);
    runz += __shfl(iz, 63, 64);
  }

  // ---- Phase 3: block scan over wave totals ----
  __shared__ float wtot[3][NW];
  __shared__ float redbuf[NW];
  if (lane == 0) { wtot[0][wave] = runx; wtot[1][wave] = runy; wtot[2][wave] = runz; }
  __syncthreads();

  float wx = 0.f, wy = 0.f, wz = 0.f;
  #pragma unroll
  for (int w = 0; w < NW; ++w) {
    if (w < wave) { wx += wtot[0][w]; wy += wtot[1][w]; wz += wtot[2][w]; }
  }

  const float ox = o3[b * 3 + 0] - o2[b * 3 + 0];
  const float oy = o3[b * 3 + 1] - o2[b * 3 + 1];
  const float oz = o3[b * 3 + 2] - o2[b * 3 + 2];
  const float bx = ox + wx, by = oy + wy, bz = oz + wz;

  // ---- Phase 4: abs over in-register prefixes ----
  float acc = 0.f;
  #pragma unroll
  for (int g = 0; g < 4; ++g) {
    const float gx = bx + segx[g], gy = by + segy[g], gz = bz + segz[g];
    #pragma unroll
    for (int k = 0; k < 4; ++k) {
      acc += fabsf(gx + px[g][k]) + fabsf(gy + py[g][k]) + fabsf(gz + pz[g][k]);
    }
  }
  if (t == 0) acc += fabsf(ox) + fabsf(oy) + fabsf(oz);  // j=0 cumsum term

  // ---- block reduction + one atomic per row ----
  #pragma unroll
  for (int off = 32; off > 0; off >>= 1) acc += __shfl_down(acc, off, 64);
  if (lane == 0) redbuf[wave] = acc;
  __syncthreads();
  if (t == 0) {
    float s = 0.f;
    #pragma unroll
    for (int w = 0; w < NW; ++w) s += redbuf[w];
    atomicAdd(out, s * (1.0f / (float)(NPTS + 1)));
  }
}

extern "C" void kernel_launch(void* const* d_in, const int* in_sizes, int n_in,
                              void* d_out, int out_size, void* d_ws, size_t ws_size,
                              hipStream_t stream) {
  const float* o3 = (const float*)d_in[0];  // origin_3D      (B,3,1)
  const float* s3 = (const float*)d_in[1];  // spherical_3D   (B,3,N)
  const float* o2 = (const float*)d_in[2];  // origin_2D      (B,3,1)
  const float* s2 = (const float*)d_in[3];  // spherical_2D   (B,3,N)
  const float* df = (const float*)d_in[4];  // deformation    (B,2,N)
  float* out = (float*)d_out;

  // out accumulates via atomicAdd; harness doesn't re-zero between replays.
  hipMemsetAsync(out, 0, sizeof(float) * out_size, stream);
  row_loss_kernel<<<NBATCH, THREADS, 0, stream>>>(o3, s3, o2, s2, df, out);
}